// Round 1
// baseline (48.295 us; speedup 1.0000x reference)
//
#include <hip/hip_runtime.h>
#include <math.h>

// out[b,o] = min_i(W[o,i]+X[b,i]) + max_i(W[o,i]+X[b,i])
// B=1024, OUT=1024, IN=512, fp32. Compute-bound VALU kernel (no fp32 MFMA).

constexpr int B_DIM  = 1024;
constexpr int O_DIM  = 1024;
constexpr int IN_DIM = 512;

constexpr int BM = 64;   // batch-tile
constexpr int BN = 64;   // out-tile
constexpr int BK = 32;   // k-tile
constexpr int NT = IN_DIM / BK;  // 16 k-tiles

// Byte offset into one LDS tile (k-major: row k holds 64 floats = 256 B).
// XOR swizzle on bits 4-6 spreads the transposed staging writes across banks
// (write conflicts 8-way -> 2-way=free); reads use the identical formula so
// the 16B-aligned float4 fragments stay contiguous and conflict-free.
__device__ __forceinline__ int swz(int k, int byteInRow) {
    return k * 256 + (byteInRow ^ (((k >> 2) & 7) << 4));
}

__global__ __launch_bounds__(256) void tropical_gemm(
    const float* __restrict__ X, const float* __restrict__ W,
    float* __restrict__ out) {
    // [buf][0=X,1=W][BK*BM floats]  -> 32 KB total
    __shared__ float lds[2][2][BK * BM];

    const int tid = threadIdx.x;
    const int tn  = tid & 15;   // out-dir   (0..15)
    const int tm  = tid >> 4;   // batch-dir (0..15)
    const int b0  = blockIdx.y * BM;
    const int o0  = blockIdx.x * BN;

    // staging assignment: 8 k-chunks of 4 floats x 32 rows, two row-passes
    const int kk  = tid & 7;    // k-chunk index (x4 floats)
    const int row = tid >> 3;   // 0..31

    const float* Xp = X + (size_t)(b0 + row) * IN_DIM + kk * 4;
    const float* Wp = W + (size_t)(o0 + row) * IN_DIM + kk * 4;

    float mn[4][4], mx[4][4];
#pragma unroll
    for (int i = 0; i < 4; ++i)
#pragma unroll
        for (int j = 0; j < 4; ++j) { mn[i][j] = INFINITY; mx[i][j] = -INFINITY; }

    // ---- prefetch + stage tile 0 ----
    float4 xg0 = *(const float4*)(Xp);
    float4 xg1 = *(const float4*)(Xp + 32 * IN_DIM);
    float4 wg0 = *(const float4*)(Wp);
    float4 wg1 = *(const float4*)(Wp + 32 * IN_DIM);
    Xp += BK; Wp += BK;
    {
        char* Xd = (char*)&lds[0][0][0];
        char* Wd = (char*)&lds[0][1][0];
#pragma unroll
        for (int j = 0; j < 4; ++j) {
            *(float*)(Xd + swz(kk * 4 + j, row * 4))        = ((const float*)&xg0)[j];
            *(float*)(Xd + swz(kk * 4 + j, (row + 32) * 4)) = ((const float*)&xg1)[j];
            *(float*)(Wd + swz(kk * 4 + j, row * 4))        = ((const float*)&wg0)[j];
            *(float*)(Wd + swz(kk * 4 + j, (row + 32) * 4)) = ((const float*)&wg1)[j];
        }
    }
    __syncthreads();

    int cur = 0;
    for (int t = 0; t < NT; ++t) {
        const bool has_next = (t + 1 < NT);
        if (has_next) {  // issue next tile's global loads early (hide latency)
            xg0 = *(const float4*)(Xp);
            xg1 = *(const float4*)(Xp + 32 * IN_DIM);
            wg0 = *(const float4*)(Wp);
            wg1 = *(const float4*)(Wp + 32 * IN_DIM);
            Xp += BK; Wp += BK;
        }

        const char* Xs = (const char*)&lds[cur][0][0];
        const char* Ws = (const char*)&lds[cur][1][0];
#pragma unroll
        for (int k = 0; k < BK; k += 2) {
            float4 x0 = *(const float4*)(Xs + swz(k,     tm * 16));
            float4 w0 = *(const float4*)(Ws + swz(k,     tn * 16));
            float4 x1 = *(const float4*)(Xs + swz(k + 1, tm * 16));
            float4 w1 = *(const float4*)(Ws + swz(k + 1, tn * 16));
            const float xs0[4] = {x0.x, x0.y, x0.z, x0.w};
            const float ws0[4] = {w0.x, w0.y, w0.z, w0.w};
            const float xs1[4] = {x1.x, x1.y, x1.z, x1.w};
            const float ws1[4] = {w1.x, w1.y, w1.z, w1.w};
#pragma unroll
            for (int i = 0; i < 4; ++i)
#pragma unroll
                for (int j = 0; j < 4; ++j) {
                    float s0 = xs0[i] + ws0[j];
                    float s1 = xs1[i] + ws1[j];
                    // nested fminf/fmaxf -> v_min3_f32 / v_max3_f32
                    mn[i][j] = fminf(fminf(s0, s1), mn[i][j]);
                    mx[i][j] = fmaxf(fmaxf(s0, s1), mx[i][j]);
                }
        }

        if (has_next) {  // stage next tile into the other buffer
            char* Xd = (char*)&lds[cur ^ 1][0][0];
            char* Wd = (char*)&lds[cur ^ 1][1][0];
#pragma unroll
            for (int j = 0; j < 4; ++j) {
                *(float*)(Xd + swz(kk * 4 + j, row * 4))        = ((const float*)&xg0)[j];
                *(float*)(Xd + swz(kk * 4 + j, (row + 32) * 4)) = ((const float*)&xg1)[j];
                *(float*)(Wd + swz(kk * 4 + j, row * 4))        = ((const float*)&wg0)[j];
                *(float*)(Wd + swz(kk * 4 + j, (row + 32) * 4)) = ((const float*)&wg1)[j];
            }
            __syncthreads();
            cur ^= 1;
        }
    }

    // ---- epilogue: out = min + max, float4 stores ----
    float* op = out + (size_t)(b0 + tm * 4) * O_DIM + o0 + tn * 4;
#pragma unroll
    for (int i = 0; i < 4; ++i) {
        float4 r;
        r.x = mn[i][0] + mx[i][0];
        r.y = mn[i][1] + mx[i][1];
        r.z = mn[i][2] + mx[i][2];
        r.w = mn[i][3] + mx[i][3];
        *(float4*)(op + (size_t)i * O_DIM) = r;
    }
}

extern "C" void kernel_launch(void* const* d_in, const int* in_sizes, int n_in,
                              void* d_out, int out_size, void* d_ws, size_t ws_size,
                              hipStream_t stream) {
    (void)in_sizes; (void)n_in; (void)d_ws; (void)ws_size; (void)out_size;
    const float* X = (const float*)d_in[0];
    const float* W = (const float*)d_in[1];
    float* out     = (float*)d_out;

    dim3 grid(O_DIM / BN, B_DIM / BM);  // (16, 16) = 256 blocks = 1/CU
    tropical_gemm<<<grid, dim3(256), 0, stream>>>(X, W, out);
}